// Round 2
// baseline (760.151 us; speedup 1.0000x reference)
//
#include <hip/hip_runtime.h>
#include <stdint.h>

typedef unsigned int u32;
typedef unsigned short u16;

#define NSTEP 16
#define DTS (1.0f/16.0f)

#define TAB_FLAG 0
#define TAB_W2   8
#define TAB_W2M  72
#define TAB_WT   136

__device__ __forceinline__ float b2f(u16 h){ return __uint_as_float(((u32)h) << 16); }
__device__ __forceinline__ u32 f2b(float f){
  u32 u = __float_as_uint(f);
  return (u + 0x7fffu + ((u >> 16) & 1u)) >> 16;   // RNE to bf16
}
__host__ __device__ constexpr int TRI(int i, int j){ return i*7 - (i*(i-1))/2 + (j-i-1); }

// ws (floats): [0] dtype flag (1.0 = bf16 inputs, 0.0 = fp32 inputs)
//              [8..71]   W2 ; [72..135] W2 - W2^T
//              [136 + s*32 + e]  antisym(W0 + t(s)*W1) upper-tri, e<28, s = step*4+stage
__global__ void prep_kernel(const void* __restrict__ W0v, const void* __restrict__ W1v,
                            const void* __restrict__ W2v, float* __restrict__ ws)
{
  __shared__ int sflag;
  __shared__ float sW0[64], sW1[64], sW2[64];
  int t = threadIdx.x;

  if (t == 0) {
    // classify dtype: decode W2 as bf16; genuine bf16 data (0.1*N(0,1)) is always
    // sane; fp32 data misread as bf16 pairs yields huge/NaN values w.p. ~1-3e-9.
    const u16* w2h = (const u16*)W2v;
    int ok = 1;
    for (int x = 0; x < 64; ++x) {
      float v = b2f(w2h[x]);
      if (!(v > -1024.0f && v < 1024.0f)) { ok = 0; break; }  // NaN fails too
    }
    sflag = ok;
    ws[TAB_FLAG] = (float)ok;
  }
  __syncthreads();
  int isbf = sflag;

  if (t < 64) {
    if (isbf) {
      sW0[t] = b2f(((const u16*)W0v)[t]);
      sW1[t] = b2f(((const u16*)W1v)[t]);
      sW2[t] = b2f(((const u16*)W2v)[t]);
    } else {
      sW0[t] = ((const float*)W0v)[t];
      sW1[t] = ((const float*)W1v)[t];
      sW2[t] = ((const float*)W2v)[t];
    }
  }
  __syncthreads();

  if (t < 64) {
    int i = t >> 3, j = t & 7;
    ws[TAB_W2  + t] = sW2[t];
    ws[TAB_W2M + t] = sW2[t] - sW2[j*8+i];
  }
  for (int idx = t; idx < 64*28; idx += 256) {
    int s = idx / 28;
    int e = idx - s*28;
    int i = 0, r = e;
    while (r >= 7 - i) { r -= 7 - i; ++i; }
    int j = i + 1 + r;
    int step = s >> 2, st = s & 3;
    float toff = (st == 0) ? 0.0f : ((st == 3) ? 1.0f : 0.5f);
    float tt = ((float)step + toff) * DTS;
    float w0a = 0.5f*(sW0[i*8+j] - sW0[j*8+i]);
    float w1a = 0.5f*(sW1[i*8+j] - sW1[j*8+i]);
    ws[TAB_WT + s*32 + e] = fmaf(tt, w1a, w0a);
  }
}

__global__ __launch_bounds__(256, 1) void flow_kernel(
    const void* __restrict__ U0v, const void* __restrict__ EPSv,
    const float* __restrict__ ws, void* __restrict__ outv, int B)
{
  int b = blockIdx.x * 256 + threadIdx.x;
  if (b >= B) return;
  const int isbf = (ws[TAB_FLAG] != 0.0f);

  float U[64], V[64], E[64];
  if (isbf) {
    const uint4* pu = (const uint4*)((const u16*)U0v + (size_t)b*64);
    const uint4* pv = (const uint4*)((const u16*)EPSv + (size_t)b*64);
    #pragma unroll
    for (int q = 0; q < 8; ++q) {
      uint4 xu = pu[q];
      uint4 xv = pv[q];
      U[8*q+0]=b2f((u16)(xu.x&0xffffu)); U[8*q+1]=b2f((u16)(xu.x>>16));
      U[8*q+2]=b2f((u16)(xu.y&0xffffu)); U[8*q+3]=b2f((u16)(xu.y>>16));
      U[8*q+4]=b2f((u16)(xu.z&0xffffu)); U[8*q+5]=b2f((u16)(xu.z>>16));
      U[8*q+6]=b2f((u16)(xu.w&0xffffu)); U[8*q+7]=b2f((u16)(xu.w>>16));
      V[8*q+0]=b2f((u16)(xv.x&0xffffu)); V[8*q+1]=b2f((u16)(xv.x>>16));
      V[8*q+2]=b2f((u16)(xv.y&0xffffu)); V[8*q+3]=b2f((u16)(xv.y>>16));
      V[8*q+4]=b2f((u16)(xv.z&0xffffu)); V[8*q+5]=b2f((u16)(xv.z>>16));
      V[8*q+6]=b2f((u16)(xv.w&0xffffu)); V[8*q+7]=b2f((u16)(xv.w>>16));
    }
  } else {
    const float4* pu = (const float4*)((const float*)U0v + (size_t)b*64);
    const float4* pv = (const float4*)((const float*)EPSv + (size_t)b*64);
    #pragma unroll
    for (int q = 0; q < 16; ++q) {
      float4 xu = pu[q];
      float4 xv = pv[q];
      U[4*q+0]=xu.x; U[4*q+1]=xu.y; U[4*q+2]=xu.z; U[4*q+3]=xu.w;
      V[4*q+0]=xv.x; V[4*q+1]=xv.y; V[4*q+2]=xv.z; V[4*q+3]=xv.w;
    }
  }

  // E = V * (W2 - W2^T)  (per-batch constant)
  {
    const float* W2m = ws + TAB_W2M;
    #pragma unroll
    for (int i = 0; i < 8; ++i) {
      #pragma unroll
      for (int j = 0; j < 8; ++j) {
        float s = V[i*8+0] * W2m[0*8+j];
        #pragma unroll
        for (int k = 1; k < 8; ++k) s = fmaf(V[i*8+k], W2m[k*8+j], s);
        E[i*8+j] = s;
      }
    }
  }

  const float* W2f = ws + TAB_W2;
  float lj = 0.0f;

  #pragma unroll 1
  for (int step = 0; step < NSTEP; ++step) {
    float Us[64], acc[64];
    #pragma unroll
    for (int x = 0; x < 64; ++x) { Us[x] = U[x]; acc[x] = 0.0f; }

    #pragma unroll 1
    for (int stage = 0; stage < 4; ++stage) {
      const float* wt = ws + TAB_WT + (size_t)(((step << 2) | stage) << 5);

      // A = U * W2
      float A[64];
      #pragma unroll
      for (int i = 0; i < 8; ++i) {
        #pragma unroll
        for (int j = 0; j < 8; ++j) {
          float s = U[i*8+0] * W2f[0*8+j];
          #pragma unroll
          for (int k = 1; k < 8; ++k) s = fmaf(U[i*8+k], W2f[k*8+j], s);
          A[i*8+j] = s;
        }
      }

      // F upper triangle: F_ij = wt_ij + 0.5*(dot(A_i,U_j) - dot(A_j,U_i))
      float Fu[28];
      #pragma unroll
      for (int i = 0; i < 8; ++i) {
        #pragma unroll
        for (int j = i+1; j < 8; ++j) {
          float s = A[i*8+0] * U[j*8+0];
          #pragma unroll
          for (int k = 1; k < 8; ++k) s = fmaf(A[i*8+k], U[j*8+k], s);
          #pragma unroll
          for (int k = 0; k < 8; ++k) s = fmaf(-A[j*8+k], U[i*8+k], s);
          Fu[TRI(i,j)] = fmaf(0.5f, s, wt[TRI(i,j)]);
        }
      }

      // logj rate = 0.5 * sum_{i<j} Delta_ij * Gamma_ij
      // Delta = v U^T - U v^T ; Gamma_ij = dot(E_i,U_j) - dot(E_j,U_i)
      float Ssum = 0.0f;
      #pragma unroll
      for (int i = 0; i < 8; ++i) {
        #pragma unroll
        for (int j = i+1; j < 8; ++j) {
          float d = V[i*8+0] * U[j*8+0];
          #pragma unroll
          for (int k = 1; k < 8; ++k) d = fmaf(V[i*8+k], U[j*8+k], d);
          #pragma unroll
          for (int k = 0; k < 8; ++k) d = fmaf(-U[i*8+k], V[j*8+k], d);
          float g = E[i*8+0] * U[j*8+0];
          #pragma unroll
          for (int k = 1; k < 8; ++k) g = fmaf(E[i*8+k], U[j*8+k], g);
          #pragma unroll
          for (int k = 0; k < 8; ++k) g = fmaf(-E[j*8+k], U[i*8+k], g);
          Ssum = fmaf(d, g, Ssum);
        }
      }
      float cl = (stage == 1 || stage == 2) ? (DTS/6.0f) : (DTS/12.0f); // dt/6 * w * 0.5
      lj = fmaf(cl, Ssum, lj);

      // K = F*U (F antisym, zero diag); overwrite A (dead); acc += w*K
      float wa = (stage == 1 || stage == 2) ? 2.0f : 1.0f;
      #pragma unroll
      for (int i = 0; i < 8; ++i) {
        #pragma unroll
        for (int j = 0; j < 8; ++j) {
          float s = 0.0f;
          #pragma unroll
          for (int k = 0; k < 8; ++k) {
            if (k == i) continue;
            float fk = (i < k) ? Fu[TRI(i < k ? i : k, i < k ? k : i)]
                               : -Fu[TRI(i < k ? i : k, i < k ? k : i)];
            s = fmaf(fk, U[k*8+j], s);
          }
          A[i*8+j] = s;
          acc[i*8+j] = fmaf(wa, s, acc[i*8+j]);
        }
      }
      if (stage < 3) {
        float cs = (stage == 2) ? DTS : (0.5f*DTS);
        #pragma unroll
        for (int x = 0; x < 64; ++x) U[x] = fmaf(cs, A[x], Us[x]);
      }
    }

    #pragma unroll
    for (int x = 0; x < 64; ++x) U[x] = fmaf(DTS/6.0f, acc[x], Us[x]);
  }

  if (isbf) {
    u16* outU = (u16*)outv;
    uint4* po = (uint4*)(outU + (size_t)b*64);
    #pragma unroll
    for (int q = 0; q < 8; ++q) {
      uint4 o;
      o.x = f2b(U[8*q+0]) | (f2b(U[8*q+1]) << 16);
      o.y = f2b(U[8*q+2]) | (f2b(U[8*q+3]) << 16);
      o.z = f2b(U[8*q+4]) | (f2b(U[8*q+5]) << 16);
      o.w = f2b(U[8*q+6]) | (f2b(U[8*q+7]) << 16);
      po[q] = o;
    }
    outU[(size_t)B*64 + b] = (u16)f2b(lj);
  } else {
    float* outU = (float*)outv;
    float4* po = (float4*)(outU + (size_t)b*64);
    #pragma unroll
    for (int q = 0; q < 16; ++q) {
      float4 o;
      o.x = U[4*q+0]; o.y = U[4*q+1]; o.z = U[4*q+2]; o.w = U[4*q+3];
      po[q] = o;
    }
    outU[(size_t)B*64 + b] = lj;
  }
}

extern "C" void kernel_launch(void* const* d_in, const int* in_sizes, int n_in,
                              void* d_out, int out_size, void* d_ws, size_t ws_size,
                              hipStream_t stream) {
  const void* U0  = d_in[0];
  const void* EPS = d_in[1];
  const void* W0  = d_in[2];
  const void* W1  = d_in[3];
  const void* W2  = d_in[4];
  float* ws = (float*)d_ws;
  int B = in_sizes[0] / 64;

  hipLaunchKernelGGL(prep_kernel, dim3(1), dim3(256), 0, stream, W0, W1, W2, ws);
  hipLaunchKernelGGL(flow_kernel, dim3((B + 255) / 256), dim3(256), 0, stream,
                     U0, EPS, ws, d_out, B);
}

// Round 3
// 629.216 us; speedup vs baseline: 1.2081x; 1.2081x over previous
//
#include <hip/hip_runtime.h>
#include <stdint.h>

typedef unsigned int u32;
typedef unsigned short u16;
typedef float v2f __attribute__((ext_vector_type(2)));

#define NSTEP 16
#define DTS (1.0f/16.0f)

#define TAB_FLAG 0
#define TAB_W2   8
#define TAB_W2M  72
#define TAB_WT   136

__device__ __forceinline__ float b2f(u16 h){ return __uint_as_float(((u32)h) << 16); }
__device__ __forceinline__ u32 f2b(float f){
  u32 u = __float_as_uint(f);
  return (u + 0x7fffu + ((u >> 16) & 1u)) >> 16;   // RNE to bf16
}
__host__ __device__ constexpr int TRI(int i, int j){ return i*7 - (i*(i-1))/2 + (j-i-1); }

// ws (floats): [0] dtype flag (1.0 = bf16 inputs, 0.0 = fp32)
//              [8..71] W2 ; [72..135] W2 - W2^T
//              [136 + s*32 + e] antisym(W0 + t(s)*W1) upper-tri, e<28, s = step*4+stage
__global__ void prep_kernel(const void* __restrict__ W0v, const void* __restrict__ W1v,
                            const void* __restrict__ W2v, float* __restrict__ ws)
{
  __shared__ int sflag;
  __shared__ float sW0[64], sW1[64], sW2[64];
  int t = threadIdx.x;

  if (t == 0) {
    const u16* w2h = (const u16*)W2v;
    int ok = 1;
    for (int x = 0; x < 64; ++x) {
      float v = b2f(w2h[x]);
      if (!(v > -1024.0f && v < 1024.0f)) { ok = 0; break; }
    }
    sflag = ok;
    ws[TAB_FLAG] = (float)ok;
  }
  __syncthreads();
  int isbf = sflag;

  if (t < 64) {
    if (isbf) {
      sW0[t] = b2f(((const u16*)W0v)[t]);
      sW1[t] = b2f(((const u16*)W1v)[t]);
      sW2[t] = b2f(((const u16*)W2v)[t]);
    } else {
      sW0[t] = ((const float*)W0v)[t];
      sW1[t] = ((const float*)W1v)[t];
      sW2[t] = ((const float*)W2v)[t];
    }
  }
  __syncthreads();

  if (t < 64) {
    int i = t >> 3, j = t & 7;
    ws[TAB_W2  + t] = sW2[t];
    ws[TAB_W2M + t] = sW2[t] - sW2[j*8+i];
  }
  for (int idx = t; idx < 64*28; idx += 256) {
    int s = idx / 28;
    int e = idx - s*28;
    int i = 0, r = e;
    while (r >= 7 - i) { r -= 7 - i; ++i; }
    int j = i + 1 + r;
    int step = s >> 2, st = s & 3;
    float toff = (st == 0) ? 0.0f : ((st == 3) ? 1.0f : 0.5f);
    float tt = ((float)step + toff) * DTS;
    float w0a = 0.5f*(sW0[i*8+j] - sW0[j*8+i]);
    float w1a = 0.5f*(sW1[i*8+j] - sW1[j*8+i]);
    ws[TAB_WT + s*32 + e] = fmaf(tt, w1a, w0a);
  }
}

// scalar element (i,k) from a v2f-packed 8x8 row-major matrix
#define SC(arr,i,k) (((k)&1) ? arr[(i)*4+((k)>>1)].y : arr[(i)*4+((k)>>1)].x)

__global__ void __attribute__((amdgpu_flat_work_group_size(256,256), amdgpu_waves_per_eu(1,1)))
flow_kernel(const void* __restrict__ U0v, const void* __restrict__ EPSv,
            const float* __restrict__ ws, void* __restrict__ outv, int B)
{
  int b = blockIdx.x * 256 + threadIdx.x;
  if (b >= B) return;
  const int isbf = (ws[TAB_FLAG] != 0.0f);

  v2f U2[32], V2[32], E2[32];
  if (isbf) {
    const uint4* pu = (const uint4*)((const u16*)U0v + (size_t)b*64);
    const uint4* pv = (const uint4*)((const u16*)EPSv + (size_t)b*64);
    #pragma unroll
    for (int q = 0; q < 8; ++q) {
      uint4 xu = pu[q];
      uint4 xv = pv[q];
      U2[4*q+0] = (v2f){b2f((u16)(xu.x&0xffffu)), b2f((u16)(xu.x>>16))};
      U2[4*q+1] = (v2f){b2f((u16)(xu.y&0xffffu)), b2f((u16)(xu.y>>16))};
      U2[4*q+2] = (v2f){b2f((u16)(xu.z&0xffffu)), b2f((u16)(xu.z>>16))};
      U2[4*q+3] = (v2f){b2f((u16)(xu.w&0xffffu)), b2f((u16)(xu.w>>16))};
      V2[4*q+0] = (v2f){b2f((u16)(xv.x&0xffffu)), b2f((u16)(xv.x>>16))};
      V2[4*q+1] = (v2f){b2f((u16)(xv.y&0xffffu)), b2f((u16)(xv.y>>16))};
      V2[4*q+2] = (v2f){b2f((u16)(xv.z&0xffffu)), b2f((u16)(xv.z>>16))};
      V2[4*q+3] = (v2f){b2f((u16)(xv.w&0xffffu)), b2f((u16)(xv.w>>16))};
    }
  } else {
    const float4* pu = (const float4*)((const float*)U0v + (size_t)b*64);
    const float4* pv = (const float4*)((const float*)EPSv + (size_t)b*64);
    #pragma unroll
    for (int q = 0; q < 16; ++q) {
      float4 xu = pu[q];
      float4 xv = pv[q];
      U2[2*q+0] = (v2f){xu.x, xu.y};  U2[2*q+1] = (v2f){xu.z, xu.w};
      V2[2*q+0] = (v2f){xv.x, xv.y};  V2[2*q+1] = (v2f){xv.z, xv.w};
    }
  }

  const v2f* W2p  = (const v2f*)(ws + TAB_W2);    // row k: W2p[k*4+jp]
  const v2f* W2mp = (const v2f*)(ws + TAB_W2M);

  // E = V * (W2 - W2^T)  (per-batch constant)
  #pragma unroll
  for (int i = 0; i < 8; ++i) {
    #pragma unroll
    for (int jp = 0; jp < 4; ++jp) {
      v2f a = SC(V2,i,0) * W2mp[0*4+jp];
      #pragma unroll
      for (int k = 1; k < 8; ++k) a += SC(V2,i,k) * W2mp[k*4+jp];
      E2[i*4+jp] = a;
    }
  }

  float lj = 0.0f;

  #pragma unroll 1
  for (int step = 0; step < NSTEP; ++step) {
    v2f Us2[32], acc2[32];
    #pragma unroll
    for (int x = 0; x < 32; ++x) { Us2[x] = U2[x]; acc2[x] = (v2f){0.0f, 0.0f}; }

    #pragma unroll 1
    for (int stage = 0; stage < 4; ++stage) {
      const float* wt = ws + TAB_WT + (size_t)(((step << 2) | stage) << 5);

      // A = U * W2
      v2f A2[32];
      #pragma unroll
      for (int i = 0; i < 8; ++i) {
        #pragma unroll
        for (int jp = 0; jp < 4; ++jp) {
          v2f a = SC(U2,i,0) * W2p[0*4+jp];
          #pragma unroll
          for (int k = 1; k < 8; ++k) a += SC(U2,i,k) * W2p[k*4+jp];
          A2[i*4+jp] = a;
        }
      }

      // F upper tri: F_ij = wt_ij + 0.5*(dot(A_i,U_j) - dot(A_j,U_i))
      float Fu[28];
      #pragma unroll
      for (int i = 0; i < 8; ++i) {
        #pragma unroll
        for (int j = i+1; j < 8; ++j) {
          v2f s2 = A2[i*4+0] * U2[j*4+0];
          #pragma unroll
          for (int kp = 1; kp < 4; ++kp) s2 += A2[i*4+kp] * U2[j*4+kp];
          #pragma unroll
          for (int kp = 0; kp < 4; ++kp) s2 -= A2[j*4+kp] * U2[i*4+kp];
          Fu[TRI(i,j)] = fmaf(0.5f, s2.x + s2.y, wt[TRI(i,j)]);
        }
      }

      // logj rate = 0.5 * sum_{i<j} Delta_ij * Gamma_ij
      float Ssum = 0.0f;
      #pragma unroll
      for (int i = 0; i < 8; ++i) {
        #pragma unroll
        for (int j = i+1; j < 8; ++j) {
          v2f d2 = V2[i*4+0] * U2[j*4+0];
          #pragma unroll
          for (int kp = 1; kp < 4; ++kp) d2 += V2[i*4+kp] * U2[j*4+kp];
          #pragma unroll
          for (int kp = 0; kp < 4; ++kp) d2 -= U2[i*4+kp] * V2[j*4+kp];
          v2f g2 = E2[i*4+0] * U2[j*4+0];
          #pragma unroll
          for (int kp = 1; kp < 4; ++kp) g2 += E2[i*4+kp] * U2[j*4+kp];
          #pragma unroll
          for (int kp = 0; kp < 4; ++kp) g2 -= E2[j*4+kp] * U2[i*4+kp];
          Ssum = fmaf(d2.x + d2.y, g2.x + g2.y, Ssum);
        }
      }
      float cl = (stage == 1 || stage == 2) ? (DTS/6.0f) : (DTS/12.0f); // dt/6 * w * 0.5
      lj = fmaf(cl, Ssum, lj);

      // K = F*U (antisym F, zero diag), overwrite A2; acc += w*K; stage<3: U = Us + cs*K
      float wa = (stage == 1 || stage == 2) ? 2.0f : 1.0f;
      #pragma unroll
      for (int i = 0; i < 8; ++i) {
        #pragma unroll
        for (int jp = 0; jp < 4; ++jp) {
          const int k0 = (i == 0) ? 1 : 0;
          float f0 = (i < k0) ? Fu[TRI(i<k0?i:k0, i<k0?k0:i)] : -Fu[TRI(i<k0?i:k0, i<k0?k0:i)];
          v2f s2 = f0 * U2[k0*4+jp];
          #pragma unroll
          for (int k = 0; k < 8; ++k) {
            if (k == i || k == k0) continue;
            float fk = (i < k) ? Fu[TRI(i<k?i:k, i<k?k:i)] : -Fu[TRI(i<k?i:k, i<k?k:i)];
            s2 += fk * U2[k*4+jp];
          }
          A2[i*4+jp] = s2;
          acc2[i*4+jp] += wa * s2;
        }
      }
      if (stage < 3) {
        float cs = (stage == 2) ? DTS : (0.5f*DTS);
        #pragma unroll
        for (int x = 0; x < 32; ++x) U2[x] = Us2[x] + cs * A2[x];
      }
    }

    #pragma unroll
    for (int x = 0; x < 32; ++x) U2[x] = Us2[x] + (DTS/6.0f) * acc2[x];
  }

  if (isbf) {
    u16* outU = (u16*)outv;
    uint4* po = (uint4*)(outU + (size_t)b*64);
    #pragma unroll
    for (int q = 0; q < 8; ++q) {
      uint4 o;
      o.x = f2b(U2[4*q+0].x) | (f2b(U2[4*q+0].y) << 16);
      o.y = f2b(U2[4*q+1].x) | (f2b(U2[4*q+1].y) << 16);
      o.z = f2b(U2[4*q+2].x) | (f2b(U2[4*q+2].y) << 16);
      o.w = f2b(U2[4*q+3].x) | (f2b(U2[4*q+3].y) << 16);
      po[q] = o;
    }
    outU[(size_t)B*64 + b] = (u16)f2b(lj);
  } else {
    float* outU = (float*)outv;
    float4* po = (float4*)(outU + (size_t)b*64);
    #pragma unroll
    for (int q = 0; q < 16; ++q) {
      float4 o;
      o.x = U2[2*q].x; o.y = U2[2*q].y; o.z = U2[2*q+1].x; o.w = U2[2*q+1].y;
      po[q] = o;
    }
    outU[(size_t)B*64 + b] = lj;
  }
}

extern "C" void kernel_launch(void* const* d_in, const int* in_sizes, int n_in,
                              void* d_out, int out_size, void* d_ws, size_t ws_size,
                              hipStream_t stream) {
  const void* U0  = d_in[0];
  const void* EPS = d_in[1];
  const void* W0  = d_in[2];
  const void* W1  = d_in[3];
  const void* W2  = d_in[4];
  float* ws = (float*)d_ws;
  int B = in_sizes[0] / 64;

  hipLaunchKernelGGL(prep_kernel, dim3(1), dim3(256), 0, stream, W0, W1, W2, ws);
  hipLaunchKernelGGL(flow_kernel, dim3((B + 255) / 256), dim3(256), 0, stream,
                     U0, EPS, ws, d_out, B);
}